// Round 1
// baseline (749.030 us; speedup 1.0000x reference)
//
#include <hip/hip_runtime.h>
#include <cstdint>

#define HH 128
#define WW 128
#define NBATCH 2
#define CIN 256
#define COUT 256
#define DGN 4
#define K2 9
#define KDIM (CIN*K2)   // 2304
#define TP 16           // pixels per block
#define CH 32           // channels per chunk
#define HW (HH*WW)

// wT[(c*9+k)*256 + o] = w_adapt[o][c][k]
__global__ void wt_kernel(const float* __restrict__ w, float* __restrict__ wT) {
    int idx = blockIdx.x * blockDim.x + threadIdx.x;
    if (idx < KDIM * COUT) {
        int o = idx & 255;
        int ck = idx >> 8;
        wT[idx] = w[(size_t)o * KDIM + ck];
    }
}

__global__ __launch_bounds__(256) void deform_kernel(
    const float* __restrict__ x,
    const float* __restrict__ shape,
    const float* __restrict__ wo,
    const float* __restrict__ wT,
    float* __restrict__ out)
{
    __shared__ __align__(16) float s_lds[K2][CH][TP];   // 18432 B
    __shared__ float cw[DGN*K2][4][TP];                 // 9216 B
    __shared__ int   cidx[DGN*K2][4][TP];               // 9216 B
    __shared__ float sh_wo[144];
    __shared__ float sh_s[2][TP];

    const int tid = threadIdx.x;
    const int blk = blockIdx.x;          // n*H*(W/TP)
    const int wt_i = blk & 7;            // W/TP = 8
    const int nh = blk >> 3;
    const int h = nh & 127;
    const int n = nh >> 7;
    const int w0 = wt_i * TP;

    if (tid < 144) sh_wo[tid] = wo[tid];
    if (tid < 2 * TP) {
        int c = tid / TP, p = tid % TP;
        sh_s[c][p] = shape[((size_t)(n * 2 + c)) * HW + h * WW + w0 + p];
    }
    __syncthreads();

    // ---- coords: 16 pixels x 36 (dg,k) sets ----
    for (int s = tid; s < TP * DGN * K2; s += 256) {
        int p = s & 15;
        int dgk = s >> 4;           // dg*9 + k
        int k = dgk % 9;
        float s0 = sh_s[0][p], s1 = sh_s[1][p];
        // offset channel o = dgk*2 + comp ; w_offset[o][c] at o*2+c
        float dy = sh_wo[dgk * 4 + 0] * s0 + sh_wo[dgk * 4 + 1] * s1;
        float dx = sh_wo[dgk * 4 + 2] * s0 + sh_wo[dgk * 4 + 3] * s1;
        float py = (float)(h + (k / 3) - 1) + dy;
        float px = (float)(w0 + p + (k % 3) - 1) + dx;
        float y0f = floorf(py), x0f = floorf(px);
        float ly = py - y0f, lx = px - x0f;
        int y0 = (int)y0f, x0 = (int)x0f;
        float wgt[4] = {(1.f - ly) * (1.f - lx), (1.f - ly) * lx,
                        ly * (1.f - lx),         ly * lx};
        #pragma unroll
        for (int j = 0; j < 4; ++j) {
            int yi = y0 + (j >> 1);
            int xi = x0 + (j & 1);
            bool valid = (yi >= 0) && (yi < HH) && (xi >= 0) && (xi < WW);
            int yc = min(max(yi, 0), HH - 1);
            int xc = min(max(xi, 0), WW - 1);
            cw[dgk][j][p] = valid ? wgt[j] : 0.0f;
            cidx[dgk][j][p] = yc * WW + xc;
        }
    }
    __syncthreads();

    const int og = tid & 63;     // output-channel group: o = og*4 .. og*4+3
    const int pg = tid >> 6;     // pixel group (wave-uniform): p = pg*4 .. pg*4+3
    const int p = tid & 15;      // sampling pixel
    const int g = tid >> 4;      // sampling channel sub-group (0..15)

    float acc[4][4];
    #pragma unroll
    for (int j = 0; j < 4; ++j)
        #pragma unroll
        for (int q = 0; q < 4; ++q) acc[j][q] = 0.f;

    for (int cc = 0; cc < CIN / CH; ++cc) {
        const int dg = cc >> 1;
        const float* xn = x + ((size_t)n * CIN + cc * CH) * HW;

        // ---- sample 9 taps x 32 channels x 16 pixels into LDS ----
        #pragma unroll
        for (int k = 0; k < 9; ++k) {
            int dgk = dg * 9 + k;
            float cw0 = cw[dgk][0][p]; int i0 = cidx[dgk][0][p];
            float cw1 = cw[dgk][1][p]; int i1 = cidx[dgk][1][p];
            float cw2 = cw[dgk][2][p]; int i2 = cidx[dgk][2][p];
            float cw3 = cw[dgk][3][p]; int i3 = cidx[dgk][3][p];
            #pragma unroll
            for (int c2 = 0; c2 < 2; ++c2) {
                int c = g + (c2 << 4);
                const float* xc = xn + (size_t)c * HW;
                s_lds[k][c][p] = cw0 * xc[i0] + cw1 * xc[i1] +
                                 cw2 * xc[i2] + cw3 * xc[i3];
            }
        }
        __syncthreads();

        // ---- accumulate: 4 o x 4 px register tile per thread ----
        const float* wTc = wT + (size_t)(cc * CH) * 9 * 256;
        for (int c = 0; c < CH; ++c) {
            #pragma unroll
            for (int k = 0; k < 9; ++k) {
                const float4 wv = *(const float4*)(wTc + (size_t)(c * 9 + k) * 256 + og * 4);
                const float4 sv = *(const float4*)&s_lds[k][c][pg * 4];
                float wvv[4] = {wv.x, wv.y, wv.z, wv.w};
                float svv[4] = {sv.x, sv.y, sv.z, sv.w};
                #pragma unroll
                for (int j = 0; j < 4; ++j)
                    #pragma unroll
                    for (int q = 0; q < 4; ++q)
                        acc[j][q] = fmaf(wvv[j], svv[q], acc[j][q]);
            }
        }
        __syncthreads();
    }

    // ---- epilogue: ReLU + store ----
    #pragma unroll
    for (int j = 0; j < 4; ++j) {
        float4 r;
        r.x = fmaxf(acc[j][0], 0.f);
        r.y = fmaxf(acc[j][1], 0.f);
        r.z = fmaxf(acc[j][2], 0.f);
        r.w = fmaxf(acc[j][3], 0.f);
        size_t oidx = (((size_t)n * COUT + og * 4 + j) * HH + h) * WW + w0 + pg * 4;
        *(float4*)(out + oidx) = r;
    }
}

extern "C" void kernel_launch(void* const* d_in, const int* in_sizes, int n_in,
                              void* d_out, int out_size, void* d_ws, size_t ws_size,
                              hipStream_t stream) {
    const float* x        = (const float*)d_in[0];
    const float* shape    = (const float*)d_in[1];
    const float* w_offset = (const float*)d_in[2];
    const float* w_adapt  = (const float*)d_in[3];
    float* out = (float*)d_out;
    float* wT  = (float*)d_ws;   // 2304*256*4 = 2.36 MB

    wt_kernel<<<(KDIM * COUT + 255) / 256, 256, 0, stream>>>(w_adapt, wT);
    deform_kernel<<<NBATCH * HH * (WW / TP), 256, 0, stream>>>(x, shape, w_offset, wT, out);
}

// Round 2
// 283.117 us; speedup vs baseline: 2.6457x; 2.6457x over previous
//
#include <hip/hip_runtime.h>
#include <hip/hip_bf16.h>
#include <cstdint>

#define HH 128
#define WW 128
#define NBATCH 2
#define CIN 256
#define COUT 256
#define DGN 4
#define K2 9
#define HW (HH*WW)
#define KTOT (K2*CIN)          // 2304, K index = tap*256 + c
#define NKB (KTOT/32)          // 72 k-steps
#define NMT (COUT/16)          // 16 m-tiles

typedef __attribute__((ext_vector_type(8))) short short8;
typedef __attribute__((ext_vector_type(4))) float f32x4;

static __device__ __forceinline__ unsigned short f2bf(float f) {
    __hip_bfloat16 h = __float2bfloat16(f);
    return __builtin_bit_cast(unsigned short, h);
}

// ---- prologue: bake weights into A-fragment layout ----
// wA dword d = ((kb*16 + mt)*64 + lane)*4 + r  holds bf16 pair for
// k = kb*32 + (lane>>4)*8 + 2r {,+1},  m = mt*16 + (lane&15)
// W[m][k] = w_adapt[m][c][tap] with tap = k>>8, c = k&255
__global__ void wa_kernel(const float* __restrict__ w, unsigned int* __restrict__ wA) {
    int t = blockIdx.x * blockDim.x + threadIdx.x;
    if (t >= NKB * NMT * 64 * 4) return;
    int r  = t & 3;
    int l  = (t >> 2) & 63;
    int mt = (t >> 8) & 15;
    int kb = t >> 12;
    int m  = mt * 16 + (l & 15);
    int k0 = kb * 32 + (l >> 4) * 8 + r * 2;
    unsigned int pk = 0;
    #pragma unroll
    for (int e = 0; e < 2; ++e) {
        int k = k0 + e;
        int tap = k >> 8;
        int c = k & 255;
        float v = w[(size_t)m * (CIN * K2) + c * 9 + tap];
        pk |= ((unsigned int)f2bf(v)) << (16 * e);
    }
    wA[t] = pk;
}

// ---- main kernel: 4 waves x 16 pixels, M=256 per wave, B-frag in regs ----
__global__ __launch_bounds__(256, 2) void deform_mfma_kernel(
    const float* __restrict__ x,
    const float* __restrict__ shape,
    const float* __restrict__ wo,
    const short8* __restrict__ wAf,
    float* __restrict__ out)
{
    __shared__ __align__(16) int   s_idx[DGN*K2][64][4];   // corner byte-offsets
    __shared__ __align__(16) float s_cw [DGN*K2][64][4];   // corner weights (0 if invalid)

    const int tid = threadIdx.x;
    const int bid = blockIdx.x;          // n*128*2 + h*2 + wh
    const int wh = bid & 1;
    const int h  = (bid >> 1) & 127;
    const int n  = bid >> 8;

    // ---- coord phase: 36 (dg,tap) sets x 64 pixels ----
    for (int s = tid; s < DGN * K2 * 64; s += 256) {
        int p64 = s & 63;
        int dgk = s >> 6;                // dg*9 + tap
        int tap = dgk % 9;
        int w   = wh * 64 + p64;
        float s0 = shape[((size_t)(n * 2 + 0)) * HW + h * WW + w];
        float s1 = shape[((size_t)(n * 2 + 1)) * HW + h * WW + w];
        float dy = wo[dgk * 4 + 0] * s0 + wo[dgk * 4 + 1] * s1;
        float dx = wo[dgk * 4 + 2] * s0 + wo[dgk * 4 + 3] * s1;
        float py = (float)(h + (tap / 3) - 1) + dy;
        float px = (float)(w + (tap % 3) - 1) + dx;
        float y0f = floorf(py), x0f = floorf(px);
        float ly = py - y0f, lx = px - x0f;
        int y0 = (int)y0f, x0 = (int)x0f;
        float wgt[4] = {(1.f - ly) * (1.f - lx), (1.f - ly) * lx,
                        ly * (1.f - lx),         ly * lx};
        int4 iv; float4 wv;
        int   ivv[4]; float wvv[4];
        #pragma unroll
        for (int j = 0; j < 4; ++j) {
            int yi = y0 + (j >> 1);
            int xi = x0 + (j & 1);
            bool valid = (yi >= 0) && (yi < HH) && (xi >= 0) && (xi < WW);
            int yc = min(max(yi, 0), HH - 1);
            int xc = min(max(xi, 0), WW - 1);
            ivv[j] = (yc * WW + xc) * 4;
            wvv[j] = valid ? wgt[j] : 0.0f;
        }
        iv.x = ivv[0]; iv.y = ivv[1]; iv.z = ivv[2]; iv.w = ivv[3];
        wv.x = wvv[0]; wv.y = wvv[1]; wv.z = wvv[2]; wv.w = wvv[3];
        *(int4*)&s_idx[dgk][p64][0] = iv;
        *(float4*)&s_cw[dgk][p64][0] = wv;
    }
    __syncthreads();

    const int wave = tid >> 6;
    const int lane = tid & 63;
    const int pcol = lane & 15;          // B column = pixel
    const int quad = lane >> 4;          // k-octet within k-step
    const int px   = wave * 16 + pcol;   // pixel index within block [0,64)

    const char* xbase = (const char*)x + ((size_t)n * CIN) * (HW * 4);

    f32x4 acc[NMT];
    #pragma unroll
    for (int mt = 0; mt < NMT; ++mt) acc[mt] = (f32x4){0.f, 0.f, 0.f, 0.f};

    for (int tap = 0; tap < 9; ++tap) {
        int4 idxv; float4 cwv;
        #pragma unroll
        for (int cq = 0; cq < 8; ++cq) {
            const int kb = tap * 8 + cq;
            const int c0 = cq * 32 + quad * 8;
            if ((cq & 1) == 0) {                     // dg changes every 2 k-steps
                const int dgk = (cq >> 1) * 9 + tap; // wave-uniform
                idxv = *(const int4*)&s_idx[dgk][px][0];
                cwv  = *(const float4*)&s_cw[dgk][px][0];
            }
            const char* cb = xbase + ((size_t)c0 << 16);
            short8 bf;
            #pragma unroll
            for (int j = 0; j < 8; ++j) {
                const char* cj = cb + ((size_t)j << 16);
                float v = cwv.x * *(const float*)(cj + idxv.x)
                        + cwv.y * *(const float*)(cj + idxv.y)
                        + cwv.z * *(const float*)(cj + idxv.z)
                        + cwv.w * *(const float*)(cj + idxv.w);
                bf[j] = (short)f2bf(v);
            }
            const short8* wa = wAf + (size_t)kb * (NMT * 64) + lane;
            #pragma unroll
            for (int mt = 0; mt < NMT; ++mt) {
                acc[mt] = __builtin_amdgcn_mfma_f32_16x16x32_bf16(wa[mt * 64], bf, acc[mt], 0, 0, 0);
            }
        }
    }

    // ---- epilogue: ReLU + store (C/D: col=lane&15, row=(lane>>4)*4+r) ----
    const int wcol = wh * 64 + wave * 16 + pcol;
    float* outn = out + ((size_t)n * COUT) * HW + h * WW + wcol;
    #pragma unroll
    for (int mt = 0; mt < NMT; ++mt) {
        #pragma unroll
        for (int r = 0; r < 4; ++r) {
            int m = mt * 16 + quad * 4 + r;
            outn[(size_t)m * HW] = fmaxf(acc[mt][r], 0.f);
        }
    }
}

extern "C" void kernel_launch(void* const* d_in, const int* in_sizes, int n_in,
                              void* d_out, int out_size, void* d_ws, size_t ws_size,
                              hipStream_t stream) {
    const float* x        = (const float*)d_in[0];
    const float* shape    = (const float*)d_in[1];
    const float* w_offset = (const float*)d_in[2];
    const float* w_adapt  = (const float*)d_in[3];
    float* out = (float*)d_out;
    unsigned int* wA = (unsigned int*)d_ws;   // 72*16*64*4 dwords = 1.18 MB

    int wa_elems = NKB * NMT * 64 * 4;
    wa_kernel<<<(wa_elems + 255) / 256, 256, 0, stream>>>(w_adapt, wA);
    deform_mfma_kernel<<<NBATCH * HH * 2, 256, 0, stream>>>(
        x, shape, w_offset, (const short8*)wA, out);
}

// Round 3
// 252.529 us; speedup vs baseline: 2.9661x; 1.1211x over previous
//
#include <hip/hip_runtime.h>
#include <hip/hip_bf16.h>
#include <cstdint>

#define HH 128
#define WW 128
#define NBATCH 2
#define CIN 256
#define COUT 256
#define DGN 4
#define K2 9
#define HW (HH*WW)
#define KTOT (K2*CIN)          // 2304, K index = tap*256 + c
#define NKB (KTOT/32)          // 72 k-steps
#define NMT (COUT/16)          // 16 m-tiles

typedef __attribute__((ext_vector_type(8))) short short8;
typedef __attribute__((ext_vector_type(4))) float f32x4;

static __device__ __forceinline__ unsigned short f2bf(float f) {
    __hip_bfloat16 h = __float2bfloat16(f);
    return __builtin_bit_cast(unsigned short, h);
}
static __device__ __forceinline__ float bf2f(short s) {
    unsigned u = ((unsigned)(unsigned short)s) << 16;
    return __builtin_bit_cast(float, u);
}

// ---- prologue 1: NCHW fp32 -> NHWC bf16 ----
// xT[n][p][c], p = y*128+x; row = 256 ch * 2B = 512 B
__global__ __launch_bounds__(256) void tr_kernel(const float* __restrict__ x,
                                                 unsigned short* __restrict__ xT) {
    __shared__ float tile[64][65];
    const int b  = blockIdx.x;
    const int pt = b & 255;
    const int ct = (b >> 8) & 3;
    const int n  = b >> 10;
    const int p0 = pt * 64, c0 = ct * 64;
    const float* xn = x + (size_t)n * CIN * HW;
    const int tid = threadIdx.x;
    {
        const int tx = tid & 63, ty = tid >> 6;       // ty 0..3
        #pragma unroll
        for (int i = 0; i < 16; ++i) {
            int ch = i * 4 + ty;
            tile[ch][tx] = xn[(size_t)(c0 + ch) * HW + p0 + tx];
        }
    }
    __syncthreads();
    char* xb = (char*)xT + (size_t)n * HW * 512;
    {
        const int cx = tid & 31, pq = tid >> 5;       // pq 0..7
        #pragma unroll
        for (int i = 0; i < 8; ++i) {
            int p = i * 8 + pq;
            unsigned lo = f2bf(tile[2 * cx][p]);
            unsigned hi = f2bf(tile[2 * cx + 1][p]);
            *(unsigned*)(xb + (size_t)(p0 + p) * 512 + c0 * 2 + cx * 4) = lo | (hi << 16);
        }
    }
}

// ---- prologue 2: bake weights into A-fragment layout (bf16) ----
// wA dword d = ((kb*16 + mt)*64 + lane)*4 + r : k = kb*32 + (lane>>4)*8 + 2r{,+1}
// m = mt*16 + (lane&15);  W[m][k] = w_adapt[m][c][tap], tap = k>>8, c = k&255
__global__ void wa_kernel(const float* __restrict__ w, unsigned int* __restrict__ wA) {
    int t = blockIdx.x * blockDim.x + threadIdx.x;
    if (t >= NKB * NMT * 64 * 4) return;
    int r  = t & 3;
    int l  = (t >> 2) & 63;
    int mt = (t >> 8) & 15;
    int kb = t >> 12;
    int m  = mt * 16 + (l & 15);
    int k0 = kb * 32 + (l >> 4) * 8 + r * 2;
    unsigned int pk = 0;
    #pragma unroll
    for (int e = 0; e < 2; ++e) {
        int k = k0 + e;
        int tap = k >> 8;
        int c = k & 255;
        float v = w[(size_t)m * (CIN * K2) + c * 9 + tap];
        pk |= ((unsigned int)f2bf(v)) << (16 * e);
    }
    wA[t] = pk;
}

// ---- main: 4 waves x 16 px, M=256/wave, B-frag from NHWC bf16 vector gathers ----
__global__ __launch_bounds__(256, 4) void deform_mfma_kernel(
    const unsigned short* __restrict__ xT,
    const float* __restrict__ shape,
    const float* __restrict__ wo,
    const short8* __restrict__ wAf,
    float* __restrict__ out)
{
    __shared__ __align__(8) float s_pp[DGN*K2][64][2];   // (py,px) per (dgk, pixel): 18432 B

    const int tid = threadIdx.x;
    // XCD-chunked swizzle: 512 blocks, 8 XCDs, 64 blocks/XCD
    const int bid  = blockIdx.x;
    const int tile = (bid & 7) * 64 + (bid >> 3);
    const int wh = tile & 1;
    const int h  = (tile >> 1) & 127;
    const int n  = tile >> 8;

    // ---- coord phase: 36 (dg,tap) x 64 pixels -> (py,px) ----
    for (int s = tid; s < DGN * K2 * 64; s += 256) {
        int p64 = s & 63;
        int dgk = s >> 6;                // dg*9 + tap
        int tap = dgk % 9;
        int w   = wh * 64 + p64;
        float s0 = shape[((size_t)(n * 2 + 0)) * HW + h * WW + w];
        float s1 = shape[((size_t)(n * 2 + 1)) * HW + h * WW + w];
        float dy = wo[dgk * 4 + 0] * s0 + wo[dgk * 4 + 1] * s1;
        float dx = wo[dgk * 4 + 2] * s0 + wo[dgk * 4 + 3] * s1;
        s_pp[dgk][p64][0] = (float)(h + (tap / 3) - 1) + dy;
        s_pp[dgk][p64][1] = (float)(w + (tap % 3) - 1) + dx;
    }
    __syncthreads();

    const int wave = tid >> 6;
    const int lane = tid & 63;
    const int pcol = lane & 15;          // B column = pixel
    const int quad = lane >> 4;          // k-octet within k-step
    const int pxi  = wave * 16 + pcol;   // pixel index within block [0,64)
    const int q16  = quad * 16;          // channel byte sub-offset

    const char* xb = (const char*)xT + (size_t)n * HW * 512;

    f32x4 acc[NMT];
    #pragma unroll
    for (int mt = 0; mt < NMT; ++mt) acc[mt] = (f32x4){0.f, 0.f, 0.f, 0.f};

    for (int tap = 0; tap < 9; ++tap) {
        #pragma unroll
        for (int dg = 0; dg < DGN; ++dg) {
            const int dgk = dg * 9 + tap;
            // recompute bilinear corners from (py,px)
            float py = s_pp[dgk][pxi][0];
            float px = s_pp[dgk][pxi][1];
            float y0f = floorf(py), x0f = floorf(px);
            float ly = py - y0f, lx = px - x0f;
            int y0 = (int)y0f, x0 = (int)x0f;
            float wgt[4] = {(1.f - ly) * (1.f - lx), (1.f - ly) * lx,
                            ly * (1.f - lx),         ly * lx};
            int   ofs[4]; float cwv[4];
            #pragma unroll
            for (int j = 0; j < 4; ++j) {
                int yi = y0 + (j >> 1);
                int xi = x0 + (j & 1);
                bool valid = (yi >= 0) && (yi < HH) && (xi >= 0) && (xi < WW);
                int yc = min(max(yi, 0), HH - 1);
                int xc = min(max(xi, 0), WW - 1);
                ofs[j] = (yc * WW + xc) * 512;
                cwv[j] = valid ? wgt[j] : 0.0f;
            }
            #pragma unroll
            for (int cq2 = 0; cq2 < 2; ++cq2) {
                const int cq = dg * 2 + cq2;
                const char* cb = xb + cq * 64 + q16;
                short8 v0 = *(const short8*)(cb + ofs[0]);
                short8 v1 = *(const short8*)(cb + ofs[1]);
                short8 v2 = *(const short8*)(cb + ofs[2]);
                short8 v3 = *(const short8*)(cb + ofs[3]);
                short8 bf;
                #pragma unroll
                for (int j = 0; j < 8; ++j) {
                    float v = cwv[0] * bf2f(v0[j]) + cwv[1] * bf2f(v1[j])
                            + cwv[2] * bf2f(v2[j]) + cwv[3] * bf2f(v3[j]);
                    bf[j] = (short)f2bf(v);
                }
                const int kb = tap * 8 + cq;
                const short8* wa = wAf + (size_t)kb * (NMT * 64) + lane;
                #pragma unroll
                for (int mt = 0; mt < NMT; ++mt) {
                    acc[mt] = __builtin_amdgcn_mfma_f32_16x16x32_bf16(wa[mt * 64], bf, acc[mt], 0, 0, 0);
                }
            }
        }
    }

    // ---- epilogue: ReLU + store (C/D: col=lane&15, row=(lane>>4)*4+r) ----
    const int wcol = wh * 64 + wave * 16 + pcol;
    float* outn = out + ((size_t)n * COUT) * HW + h * WW + wcol;
    #pragma unroll
    for (int mt = 0; mt < NMT; ++mt) {
        #pragma unroll
        for (int r = 0; r < 4; ++r) {
            int m = mt * 16 + quad * 4 + r;
            outn[(size_t)m * HW] = fmaxf(acc[mt][r], 0.f);
        }
    }
}

extern "C" void kernel_launch(void* const* d_in, const int* in_sizes, int n_in,
                              void* d_out, int out_size, void* d_ws, size_t ws_size,
                              hipStream_t stream) {
    const float* x        = (const float*)d_in[0];
    const float* shape    = (const float*)d_in[1];
    const float* w_offset = (const float*)d_in[2];
    const float* w_adapt  = (const float*)d_in[3];
    float* out = (float*)d_out;

    unsigned int*   wA = (unsigned int*)d_ws;                       // 1.18 MB
    unsigned short* xT = (unsigned short*)((char*)d_ws + 0x130000); // 16.78 MB

    tr_kernel<<<NBATCH * 4 * 256, 256, 0, stream>>>(x, xT);
    int wa_elems = NKB * NMT * 64 * 4;
    wa_kernel<<<(wa_elems + 255) / 256, 256, 0, stream>>>(w_adapt, wA);
    deform_mfma_kernel<<<NBATCH * HH * 2, 256, 0, stream>>>(
        xT, shape, w_offset, (const short8*)wA, out);
}

// Round 4
// 106.270 us; speedup vs baseline: 7.0484x; 2.3763x over previous
//
#include <hip/hip_runtime.h>
#include <hip/hip_bf16.h>
#include <cstdint>

#define HH 128
#define WW 128
#define NBATCH 2
#define CIN 256
#define COUT 256
#define DGN 4
#define K2 9
#define HW (HH*WW)
#define KTOT (K2*CIN)          // 2304, K index = tap*256 + c
#define NKB (KTOT/32)          // 72 k-steps
#define NMT (COUT/16)          // 16 m-tiles
#define NITER 36               // k-step pairs

typedef __attribute__((ext_vector_type(8))) short short8;
typedef __attribute__((ext_vector_type(4))) float f32x4;

static __device__ __forceinline__ unsigned short f2bf(float f) {
    __hip_bfloat16 h = __float2bfloat16(f);
    return __builtin_bit_cast(unsigned short, h);
}
static __device__ __forceinline__ float bf2f(short s) {
    unsigned u = ((unsigned)(unsigned short)s) << 16;
    return __builtin_bit_cast(float, u);
}

// ---- prologue 1: NCHW fp32 -> NHWC bf16 (xT[n][p][c], 512B per pixel) ----
__global__ __launch_bounds__(256) void tr_kernel(const float* __restrict__ x,
                                                 unsigned short* __restrict__ xT) {
    __shared__ float tile[64][65];
    const int b  = blockIdx.x;
    const int pt = b & 255;
    const int ct = (b >> 8) & 3;
    const int n  = b >> 10;
    const int p0 = pt * 64, c0 = ct * 64;
    const float* xn = x + (size_t)n * CIN * HW;
    const int tid = threadIdx.x;
    {
        const int tx = tid & 63, ty = tid >> 6;
        #pragma unroll
        for (int i = 0; i < 16; ++i) {
            int ch = i * 4 + ty;
            tile[ch][tx] = xn[(size_t)(c0 + ch) * HW + p0 + tx];
        }
    }
    __syncthreads();
    char* xb = (char*)xT + (size_t)n * HW * 512;
    {
        const int cx = tid & 31, pq = tid >> 5;
        #pragma unroll
        for (int i = 0; i < 8; ++i) {
            int p = i * 8 + pq;
            unsigned lo = f2bf(tile[2 * cx][p]);
            unsigned hi = f2bf(tile[2 * cx + 1][p]);
            *(unsigned*)(xb + (size_t)(p0 + p) * 512 + c0 * 2 + cx * 4) = lo | (hi << 16);
        }
    }
}

// ---- prologue 2: weights -> A-fragment layout (bf16) ----
// wA dword ((kb*16+mt)*64+lane)*4+r : k = kb*32+(lane>>4)*8+2r{,+1}, m = mt*16+(lane&15)
__global__ void wa_kernel(const float* __restrict__ w, unsigned int* __restrict__ wA) {
    int t = blockIdx.x * blockDim.x + threadIdx.x;
    if (t >= NKB * NMT * 64 * 4) return;
    int r  = t & 3;
    int l  = (t >> 2) & 63;
    int mt = (t >> 8) & 15;
    int kb = t >> 12;
    int m  = mt * 16 + (l & 15);
    int k0 = kb * 32 + (l >> 4) * 8 + r * 2;
    unsigned int pk = 0;
    #pragma unroll
    for (int e = 0; e < 2; ++e) {
        int k = k0 + e;
        int tap = k >> 8;
        int c = k & 255;
        float v = w[(size_t)m * (CIN * K2) + c * 9 + tap];
        pk |= ((unsigned int)f2bf(v)) << (16 * e);
    }
    wA[t] = pk;
}

// ---- main: 8 waves, 64 px, M=256; LDS-shared B-frags, double-buffered ----
__global__ __launch_bounds__(512, 4) void deform_mfma_kernel(
    const unsigned short* __restrict__ xT,
    const float* __restrict__ shape,
    const float* __restrict__ wo,
    const short8* __restrict__ wAf,
    float* __restrict__ out)
{
    __shared__ __align__(16) char smem[34816];
    float*  s_pp = (float*)smem;               // [36][64][2]  18432 B
    short8* bufB = (short8*)(smem + 18432);    // [2][2][4][64] 16384 B

    const int tid = threadIdx.x;
    const int bid = blockIdx.x;                    // 512 blocks
    const int tile = (bid & 7) * 64 + (bid >> 3);  // XCD-chunked swizzle
    const int wh = tile & 1;
    const int h  = (tile >> 1) & 127;
    const int n  = tile >> 8;

    // ---- coord phase: 36 (dg,tap) x 64 px -> (py,px) ----
    for (int s = tid; s < DGN * K2 * 64; s += 512) {
        int p64 = s & 63;
        int dgk = s >> 6;
        int tap = dgk % 9;
        int w   = wh * 64 + p64;
        float s0 = shape[((size_t)(n * 2 + 0)) * HW + h * WW + w];
        float s1 = shape[((size_t)(n * 2 + 1)) * HW + h * WW + w];
        float dy = wo[dgk * 4 + 0] * s0 + wo[dgk * 4 + 1] * s1;
        float dx = wo[dgk * 4 + 2] * s0 + wo[dgk * 4 + 3] * s1;
        s_pp[(dgk * 64 + p64) * 2 + 0] = (float)(h + (tap / 3) - 1) + dy;
        s_pp[(dgk * 64 + p64) * 2 + 1] = (float)(w + (tap % 3) - 1) + dx;
    }
    __syncthreads();

    const int wave = tid >> 6;
    const int lane = tid & 63;
    const int pcol = lane & 15;
    const int quad = lane >> 4;
    const int kbh  = wave >> 2;          // this wave builds k-half kbh
    const int pxg  = wave & 3;           // ... for pixel group pxg
    const int bpx  = pxg * 16 + pcol;    // build pixel (block-local)
    const int q16  = quad * 16;          // channel byte sub-offset

    const char* xb = (const char*)xT + (size_t)n * HW * 512;

    f32x4 acc[2][4];
    #pragma unroll
    for (int a = 0; a < 2; ++a)
        #pragma unroll
        for (int b = 0; b < 4; ++b) acc[a][b] = (f32x4){0.f, 0.f, 0.f, 0.f};

    // corner math for build task at iteration i1
    auto corners = [&](int i1, int ofs[4], float cwv[4]) {
        int dgk = (i1 & 3) * 9 + (i1 >> 2);
        float py = s_pp[(dgk * 64 + bpx) * 2 + 0];
        float px = s_pp[(dgk * 64 + bpx) * 2 + 1];
        float y0f = floorf(py), x0f = floorf(px);
        float ly = py - y0f, lx = px - x0f;
        int y0 = (int)y0f, x0 = (int)x0f;
        float wgt[4] = {(1.f - ly) * (1.f - lx), (1.f - ly) * lx,
                        ly * (1.f - lx),         ly * lx};
        #pragma unroll
        for (int j = 0; j < 4; ++j) {
            int yi = y0 + (j >> 1);
            int xi = x0 + (j & 1);
            bool valid = (yi >= 0) && (yi < HH) && (xi >= 0) && (xi < WW);
            int yc = min(max(yi, 0), HH - 1);
            int xc = min(max(xi, 0), WW - 1);
            ofs[j] = (yc * WW + xc) * 512;
            cwv[j] = valid ? wgt[j] : 0.0f;
        }
    };
    auto blend_pack = [&](const short8& v0, const short8& v1, const short8& v2,
                          const short8& v3, const float cwv[4]) -> short8 {
        short8 bf;
        #pragma unroll
        for (int j = 0; j < 8; ++j) {
            float v = cwv[0] * bf2f(v0[j]) + cwv[1] * bf2f(v1[j])
                    + cwv[2] * bf2f(v2[j]) + cwv[3] * bf2f(v3[j]);
            bf[j] = (short)f2bf(v);
        }
        return bf;
    };

    // ---- prologue: build iteration 0 into buf0 ----
    {
        int ofs[4]; float cwv[4];
        corners(0, ofs, cwv);
        const char* cb = xb + (size_t)(kbh * 64 + q16);  // cq = kbh at i1=0
        short8 v0 = *(const short8*)(cb + ofs[0]);
        short8 v1 = *(const short8*)(cb + ofs[1]);
        short8 v2 = *(const short8*)(cb + ofs[2]);
        short8 v3 = *(const short8*)(cb + ofs[3]);
        bufB[((0 * 2 + kbh) * 4 + pxg) * 64 + lane] = blend_pack(v0, v1, v2, v3, cwv);
    }
    __syncthreads();

    // ---- main loop: 36 k-pair iterations ----
    for (int i = 0; i < NITER; ++i) {
        const int cur = i & 1;
        const bool do_build = (i + 1 < NITER);
        short8 v0, v1, v2, v3;
        float cwv[4];
        if (do_build) {
            int ofs[4];
            int i1 = i + 1;
            corners(i1, ofs, cwv);
            int cq = 2 * (i1 & 3) + kbh;
            const char* cb = xb + (size_t)(cq * 64 + q16);
            v0 = *(const short8*)(cb + ofs[0]);
            v1 = *(const short8*)(cb + ofs[1]);
            v2 = *(const short8*)(cb + ofs[2]);
            v3 = *(const short8*)(cb + ofs[3]);
        }

        // MFMA phase: consume buf[cur]; this wave's m-tiles = 2*wave, 2*wave+1
        const short8* wa = wAf + (size_t)(2 * i) * (NMT * 64) + (wave * 2) * 64 + lane;
        #pragma unroll
        for (int kb2 = 0; kb2 < 2; ++kb2) {
            short8 a0 = wa[kb2 * (NMT * 64)];
            short8 a1 = wa[kb2 * (NMT * 64) + 64];
            #pragma unroll
            for (int pg = 0; pg < 4; ++pg) {
                short8 bfr = bufB[((cur * 2 + kb2) * 4 + pg) * 64 + lane];
                acc[0][pg] = __builtin_amdgcn_mfma_f32_16x16x32_bf16(a0, bfr, acc[0][pg], 0, 0, 0);
                acc[1][pg] = __builtin_amdgcn_mfma_f32_16x16x32_bf16(a1, bfr, acc[1][pg], 0, 0, 0);
            }
        }

        if (do_build) {
            bufB[((((i + 1) & 1) * 2 + kbh) * 4 + pxg) * 64 + lane] =
                blend_pack(v0, v1, v2, v3, cwv);
        }
        __syncthreads();
    }

    // ---- epilogue: LDS transpose for coalesced 256B-per-m-row stores ----
    float* s_ep = (float*)(smem + wave * 4352);   // [16][68] per wave
    const int w0 = wh * 64;
    #pragma unroll
    for (int mtl = 0; mtl < 2; ++mtl) {
        #pragma unroll
        for (int pg = 0; pg < 4; ++pg)
            #pragma unroll
            for (int r = 0; r < 4; ++r)
                s_ep[(quad * 4 + r) * 68 + pg * 16 + pcol] = fmaxf(acc[mtl][pg][r], 0.f);
        __syncthreads();
        #pragma unroll
        for (int p4 = 0; p4 < 4; ++p4) {
            int mr = p4 * 4 + quad;
            f32x4 v = *(const f32x4*)&s_ep[mr * 68 + pcol * 4];
            int m = wave * 32 + mtl * 16 + mr;
            *(f32x4*)(out + ((size_t)(n * COUT + m)) * HW + h * WW + w0 + pcol * 4) = v;
        }
        __syncthreads();
    }
}

extern "C" void kernel_launch(void* const* d_in, const int* in_sizes, int n_in,
                              void* d_out, int out_size, void* d_ws, size_t ws_size,
                              hipStream_t stream) {
    const float* x        = (const float*)d_in[0];
    const float* shape    = (const float*)d_in[1];
    const float* w_offset = (const float*)d_in[2];
    const float* w_adapt  = (const float*)d_in[3];
    float* out = (float*)d_out;

    unsigned int*   wA = (unsigned int*)d_ws;                       // 1.18 MB
    unsigned short* xT = (unsigned short*)((char*)d_ws + 0x130000); // 16.78 MB

    tr_kernel<<<NBATCH * 4 * 256, 256, 0, stream>>>(x, xT);
    int wa_elems = NKB * NMT * 64 * 4;
    wa_kernel<<<(wa_elems + 255) / 256, 256, 0, stream>>>(w_adapt, wA);
    deform_mfma_kernel<<<NBATCH * HH * 2, 512, 0, stream>>>(
        xT, shape, w_offset, (const short8*)wA, out);
}